// Round 3
// baseline (382.679 us; speedup 1.0000x reference)
//
#include <hip/hip_runtime.h>
#include <hip/hip_bf16.h>
#include <cstdint>

// Problem constants (match reference)
constexpr int N_NODES = 20000;
constexpr int N_EDGES = 500000;
constexpr int IN_F    = 64;
constexpr int OUT_F   = 64;
constexpr int KS      = 5;
constexpr int K_MATS  = 25;   // KS^DIM
constexpr int G_NODES = 8;    // nodes per block in main kernel

// ---------------- CSR build ----------------

__global__ void k_hist(const int* __restrict__ ei, int* __restrict__ cnt) {
    int e = blockIdx.x * blockDim.x + threadIdx.x;
    if (e < N_EDGES) atomicAdd(&cnt[ei[e]], 1);
}

// Single-block exclusive scan of cnt[0..N) -> row_start[0..N]
__global__ __launch_bounds__(1024) void k_scan(const int* __restrict__ cnt,
                                               int* __restrict__ row_start) {
    __shared__ int sums[1024];
    const int T = 1024;
    int tid = threadIdx.x;
    const int per = (N_NODES + T - 1) / T;   // 20
    int base = tid * per;
    int s = 0;
    for (int j = 0; j < per; ++j) {
        int idx = base + j;
        if (idx < N_NODES) s += cnt[idx];
    }
    sums[tid] = s;
    __syncthreads();
    for (int off = 1; off < T; off <<= 1) {
        int v = (tid >= off) ? sums[tid - off] : 0;
        __syncthreads();
        sums[tid] += v;
        __syncthreads();
    }
    int run = (tid == 0) ? 0 : sums[tid - 1];   // exclusive prefix
    for (int j = 0; j < per; ++j) {
        int idx = base + j;
        if (idx < N_NODES) { row_start[idx] = run; run += cnt[idx]; }
    }
    if (tid == T - 1) row_start[N_NODES] = run;  // == E
}

// Per-edge spline basis + scatter into row-sorted records
__global__ void k_fill(const int* __restrict__ ei, const float* __restrict__ pseudo,
                       const int* __restrict__ row_start, int* __restrict__ fill_pos,
                       int* __restrict__ col_sorted, int* __restrict__ kpack_sorted,
                       float4* __restrict__ basis_sorted) {
    int e = blockIdx.x * blockDim.x + threadIdx.x;
    if (e >= N_EDGES) return;
    int row = ei[e];
    int col = ei[N_EDGES + e];
    float u0 = pseudo[2 * e]     * (float)(KS - 1);
    float u1 = pseudo[2 * e + 1] * (float)(KS - 1);
    int i0 = min(max((int)floorf(u0), 0), KS - 2);
    int i1 = min(max((int)floorf(u1), 0), KS - 2);
    float f0 = u0 - (float)i0;
    float f1 = u1 - (float)i1;
    // s bit0 -> dim0, bit1 -> dim1 ; flat idx = (i0+bit0)*KS + (i1+bit1)
    float b00 = (1.f - f0) * (1.f - f1);
    float b10 = f0 * (1.f - f1);
    float b01 = (1.f - f0) * f1;
    float b11 = f0 * f1;
    int k00 = i0 * KS + i1;
    int k10 = (i0 + 1) * KS + i1;
    int k01 = i0 * KS + (i1 + 1);
    int k11 = (i0 + 1) * KS + (i1 + 1);
    int pos = row_start[row] + atomicAdd(&fill_pos[row], 1);
    col_sorted[pos] = col;
    kpack_sorted[pos] = k00 | (k10 << 8) | (k01 << 16) | (k11 << 24);
    basis_sorted[pos] = make_float4(b00, b10, b01, b11);
}

// ---------------- Fused aggregate + matmul ----------------
// Block: 512 threads (8 waves) handles G_NODES=8 nodes.
// Phase 1: wave w builds agg[w][25][64] for node n0+w in LDS (no atomics).
// Phase 2: wave w handles i in [w*8, w*8+8); register-tiles all 8 nodes.
// Phase 3: deg-normalize + root weight + bias.
__global__ __launch_bounds__(512) void k_main(
    const float* __restrict__ x, const float* __restrict__ weight,
    const float* __restrict__ bias, const int* __restrict__ row_start,
    const int* __restrict__ col_sorted, const int* __restrict__ kpack,
    const float4* __restrict__ basis4, float* __restrict__ out) {

    __shared__ float agg[G_NODES][K_MATS * IN_F];  // 8*1600*4 = 51.2 KB
    __shared__ float outred[G_NODES][OUT_F];       // 2 KB

    int tid  = threadIdx.x;
    int wave = tid >> 6;
    int lane = tid & 63;
    int n0 = blockIdx.x * G_NODES;

    for (int j = tid; j < G_NODES * K_MATS * IN_F; j += 512) (&agg[0][0])[j] = 0.f;
    for (int j = tid; j < G_NODES * OUT_F; j += 512) (&outred[0][0])[j] = 0.f;
    __syncthreads();

    // ---- phase 1: per-wave edge accumulation ----
    {
        int n = n0 + wave;
        if (n < N_NODES) {
            int e0 = row_start[n], e1 = row_start[n + 1];
            for (int e = e0; e < e1; ++e) {
                int    col = col_sorted[e];
                int    kp  = kpack[e];
                float4 b   = basis4[e];
                float  xv  = x[col * IN_F + lane];
                agg[wave][((kp)       & 255) * IN_F + lane] += b.x * xv;
                agg[wave][((kp >> 8)  & 255) * IN_F + lane] += b.y * xv;
                agg[wave][((kp >> 16) & 255) * IN_F + lane] += b.z * xv;
                agg[wave][((kp >> 24) & 255) * IN_F + lane] += b.w * xv;
            }
        }
    }
    __syncthreads();

    // ---- phase 2: matmul agg[g, k, i] * W[k, i, o] ----
    float acc[G_NODES];
#pragma unroll
    for (int g = 0; g < G_NODES; ++g) acc[g] = 0.f;

    for (int k = 0; k < K_MATS; ++k) {
        float wv[8];
#pragma unroll
        for (int il = 0; il < 8; ++il)
            wv[il] = weight[(k * IN_F + wave * 8 + il) * OUT_F + lane];
#pragma unroll
        for (int g = 0; g < G_NODES; ++g) {
            const float4* ap = (const float4*)&agg[g][k * IN_F + wave * 8];
            float4 a0 = ap[0];
            float4 a1 = ap[1];
            acc[g] += a0.x * wv[0] + a0.y * wv[1] + a0.z * wv[2] + a0.w * wv[3]
                    + a1.x * wv[4] + a1.y * wv[5] + a1.z * wv[6] + a1.w * wv[7];
        }
    }
#pragma unroll
    for (int g = 0; g < G_NODES; ++g) atomicAdd(&outred[g][lane], acc[g]);
    __syncthreads();

    // ---- phase 3: normalize + root + bias ----
    {
        int g = tid >> 6, o = tid & 63;
        int nn = n0 + g;
        if (nn < N_NODES) {
            int d = row_start[nn + 1] - row_start[nn];
            float v = outred[g][o] / (float)max(d, 1);
            float r = 0.f;
            for (int i = 0; i < IN_F; ++i)
                r += x[nn * IN_F + i] * weight[(K_MATS * IN_F + i) * OUT_F + o];
            out[nn * OUT_F + o] = v + r + bias[o];
        }
    }
}

// ---------------- launch ----------------

extern "C" void kernel_launch(void* const* d_in, const int* in_sizes, int n_in,
                              void* d_out, int out_size, void* d_ws, size_t ws_size,
                              hipStream_t stream) {
    const float* x      = (const float*)d_in[0];
    const int*   ei     = (const int*)d_in[1];
    const float* pseudo = (const float*)d_in[2];
    const float* weight = (const float*)d_in[3];
    const float* bias   = (const float*)d_in[4];
    float* out = (float*)d_out;

    // workspace layout (bytes)
    char* ws = (char*)d_ws;
    int* cnt       = (int*)(ws + 0);                    // N ints
    int* fill_pos  = (int*)(ws + 80000);                // N ints
    int* row_start = (int*)(ws + 160000);               // N+1 ints
    int* col_sorted   = (int*)(ws + 240128);            // E ints   (16B aligned)
    int* kpack_sorted = (int*)(ws + 2240128);           // E ints
    float4* basis_sorted = (float4*)(ws + 4240128);     // E float4 (16B aligned)

    // zero cnt + fill_pos
    hipMemsetAsync(ws, 0, 160000, stream);

    int eb = (N_EDGES + 255) / 256;
    k_hist<<<eb, 256, 0, stream>>>(ei, cnt);
    k_scan<<<1, 1024, 0, stream>>>(cnt, row_start);
    k_fill<<<eb, 256, 0, stream>>>(ei, pseudo, row_start, fill_pos,
                                   col_sorted, kpack_sorted, basis_sorted);
    int nb = (N_NODES + G_NODES - 1) / G_NODES;  // 2500
    k_main<<<nb, 512, 0, stream>>>(x, weight, bias, row_start,
                                   col_sorted, kpack_sorted, basis_sorted, out);
}

// Round 4
// 237.801 us; speedup vs baseline: 1.6092x; 1.6092x over previous
//
#include <hip/hip_runtime.h>
#include <hip/hip_bf16.h>
#include <cstdint>

// Problem constants (match reference)
constexpr int N_NODES = 20000;
constexpr int N_EDGES = 500000;
constexpr int IN_F    = 64;
constexpr int OUT_F   = 64;
constexpr int KS      = 5;
constexpr int K_MATS  = 25;    // spline kernel matrices
constexpr int NK      = 26;    // + root weight
constexpr int ZSTRIDE = NK * OUT_F;  // 1664

typedef __attribute__((ext_vector_type(8))) short short8;
typedef __attribute__((ext_vector_type(4))) float f32x4;

__device__ __forceinline__ ushort f2bf(float f) {   // RNE float->bf16 bits
    union { float f; uint32_t u; } c; c.f = f;
    uint32_t u = c.u + 0x7FFFu + ((c.u >> 16) & 1u);
    return (ushort)(u >> 16);
}
__device__ __forceinline__ float bf2f(ushort s) {
    union { uint32_t u; float f; } c; c.u = ((uint32_t)s) << 16;
    return c.f;
}

// ---------------- CSR build (unchanged, verified) ----------------

__global__ void k_hist(const int* __restrict__ ei, int* __restrict__ cnt) {
    int e = blockIdx.x * blockDim.x + threadIdx.x;
    if (e < N_EDGES) atomicAdd(&cnt[ei[e]], 1);
}

__global__ __launch_bounds__(1024) void k_scan(const int* __restrict__ cnt,
                                               int* __restrict__ row_start) {
    __shared__ int sums[1024];
    const int T = 1024;
    int tid = threadIdx.x;
    const int per = (N_NODES + T - 1) / T;   // 20
    int base = tid * per;
    int s = 0;
    for (int j = 0; j < per; ++j) {
        int idx = base + j;
        if (idx < N_NODES) s += cnt[idx];
    }
    sums[tid] = s;
    __syncthreads();
    for (int off = 1; off < T; off <<= 1) {
        int v = (tid >= off) ? sums[tid - off] : 0;
        __syncthreads();
        sums[tid] += v;
        __syncthreads();
    }
    int run = (tid == 0) ? 0 : sums[tid - 1];
    for (int j = 0; j < per; ++j) {
        int idx = base + j;
        if (idx < N_NODES) { row_start[idx] = run; run += cnt[idx]; }
    }
    if (tid == T - 1) row_start[N_NODES] = run;
}

__global__ void k_fill(const int* __restrict__ ei, const float* __restrict__ pseudo,
                       const int* __restrict__ row_start, int* __restrict__ fill_pos,
                       int* __restrict__ col_sorted, int* __restrict__ kpack_sorted,
                       float4* __restrict__ basis_sorted) {
    int e = blockIdx.x * blockDim.x + threadIdx.x;
    if (e >= N_EDGES) return;
    int row = ei[e];
    int col = ei[N_EDGES + e];
    float u0 = pseudo[2 * e]     * (float)(KS - 1);
    float u1 = pseudo[2 * e + 1] * (float)(KS - 1);
    int i0 = min(max((int)floorf(u0), 0), KS - 2);
    int i1 = min(max((int)floorf(u1), 0), KS - 2);
    float f0 = u0 - (float)i0;
    float f1 = u1 - (float)i1;
    float b00 = (1.f - f0) * (1.f - f1);
    float b10 = f0 * (1.f - f1);
    float b01 = (1.f - f0) * f1;
    float b11 = f0 * f1;
    int k00 = i0 * KS + i1;
    int k10 = (i0 + 1) * KS + i1;
    int k01 = i0 * KS + (i1 + 1);
    int k11 = (i0 + 1) * KS + (i1 + 1);
    int pos = row_start[row] + atomicAdd(&fill_pos[row], 1);
    col_sorted[pos] = col;
    kpack_sorted[pos] = k00 | (k10 << 8) | (k01 << 16) | (k11 << 24);
    basis_sorted[pos] = make_float4(b00, b10, b01, b11);
}

// ---------------- W repack into MFMA B-fragment order (bf16) ----------------
// Wb layout: [k][ks][nf][lane][j=0..7], 16B per (k,ks,nf,lane) slot.
// B-frag for mfma_f32_16x16x32_bf16: lane holds B[k=ks*32+(lane>>4)*8+j][n=nf*16+(lane&15)].
__global__ void k_prep(const float* __restrict__ w, ushort* __restrict__ wb) {
    int t = blockIdx.x * blockDim.x + threadIdx.x;   // one 16B slot
    if (t >= NK * 2 * 4 * 64) return;
    int lane = t & 63;
    int nf   = (t >> 6) & 3;
    int ks   = (t >> 8) & 1;
    int k    = t >> 9;
    int kk0  = ks * 32 + (lane >> 4) * 8;
    int col  = nf * 16 + (lane & 15);
    ushort v[8];
#pragma unroll
    for (int j = 0; j < 8; ++j)
        v[j] = f2bf(w[(k * 64 + kk0 + j) * 64 + col]);
    uint4 p;
    p.x = (uint32_t)v[0] | ((uint32_t)v[1] << 16);
    p.y = (uint32_t)v[2] | ((uint32_t)v[3] << 16);
    p.z = (uint32_t)v[4] | ((uint32_t)v[5] << 16);
    p.w = (uint32_t)v[6] | ((uint32_t)v[7] << 16);
    ((uint4*)wb)[t] = p;
}

// ---------------- Z = x @ W[k] for all 26 k, via MFMA ----------------
// Block: 256 thr (4 waves), 16 nodes. Wave w handles k = w, w+4, ...
// A-frag: lane holds x[node0+(lane&15)][ks*32+(lane>>4)*8 + j], j=0..7.
// D-frag: col=lane&15, row=(lane>>4)*4+reg (m89-verified).
__global__ __launch_bounds__(256) void k_z(const float* __restrict__ x,
                                           const ushort* __restrict__ wb,
                                           ushort* __restrict__ z) {
    int lane = threadIdx.x & 63;
    int wave = threadIdx.x >> 6;
    int node0 = blockIdx.x * 16;
    int r  = lane & 15;
    int kg = lane >> 4;

    short8 a[2];
#pragma unroll
    for (int ks = 0; ks < 2; ++ks) {
        const float4* xp = (const float4*)(x + (node0 + r) * IN_F + ks * 32 + kg * 8);
        float4 x0 = xp[0];
        float4 x1 = xp[1];
        short8 af;
        af[0] = (short)f2bf(x0.x); af[1] = (short)f2bf(x0.y);
        af[2] = (short)f2bf(x0.z); af[3] = (short)f2bf(x0.w);
        af[4] = (short)f2bf(x1.x); af[5] = (short)f2bf(x1.y);
        af[6] = (short)f2bf(x1.z); af[7] = (short)f2bf(x1.w);
        a[ks] = af;
    }

    for (int k = wave; k < NK; k += 4) {
        f32x4 acc[4];
#pragma unroll
        for (int nf = 0; nf < 4; ++nf) acc[nf] = (f32x4){0.f, 0.f, 0.f, 0.f};

#pragma unroll
        for (int ks = 0; ks < 2; ++ks) {
#pragma unroll
            for (int nf = 0; nf < 4; ++nf) {
                union { uint4 u; short8 s; } b;
                b.u = *(const uint4*)(wb + ((((size_t)k * 2 + ks) * 4 + nf) * 64 + lane) * 8);
                acc[nf] = __builtin_amdgcn_mfma_f32_16x16x32_bf16(a[ks], b.s, acc[nf], 0, 0, 0);
            }
        }
        int rowbase = (lane >> 4) * 4;
#pragma unroll
        for (int nf = 0; nf < 4; ++nf) {
#pragma unroll
            for (int rg = 0; rg < 4; ++rg) {
                int row = rowbase + rg;
                z[(size_t)(node0 + row) * ZSTRIDE + k * 64 + nf * 16 + (lane & 15)] =
                    f2bf(acc[nf][rg]);
            }
        }
    }
}

// ---------------- Per-node gather-aggregate + epilogue ----------------
// One wave per node: acc lives in ONE VGPR (lane = output channel). No LDS.
__global__ __launch_bounds__(256) void k_out(const ushort* __restrict__ z,
        const float* __restrict__ bias, const int* __restrict__ row_start,
        const int* __restrict__ col_sorted, const int* __restrict__ kpack,
        const float4* __restrict__ basis4, float* __restrict__ out) {
    int lane = threadIdx.x & 63;
    int n = blockIdx.x * 4 + (threadIdx.x >> 6);
    if (n >= N_NODES) return;
    int e0 = row_start[n], e1 = row_start[n + 1];
    float acc = 0.f;
    for (int e = e0; e < e1; ++e) {
        int col = col_sorted[e];
        int kp  = kpack[e];
        float4 b = basis4[e];
        const ushort* zb = z + (size_t)col * ZSTRIDE;
        float z0 = bf2f(zb[((kp      ) & 255) * 64 + lane]);
        float z1 = bf2f(zb[((kp >> 8 ) & 255) * 64 + lane]);
        float z2 = bf2f(zb[((kp >> 16) & 255) * 64 + lane]);
        float z3 = bf2f(zb[((kp >> 24) & 255) * 64 + lane]);
        acc += b.x * z0 + b.y * z1 + b.z * z2 + b.w * z3;
    }
    int deg = e1 - e0;
    float root = bf2f(z[(size_t)n * ZSTRIDE + K_MATS * 64 + lane]);
    out[n * OUT_F + lane] = acc / (float)max(deg, 1) + root + bias[lane];
}

// ---------------- launch ----------------

extern "C" void kernel_launch(void* const* d_in, const int* in_sizes, int n_in,
                              void* d_out, int out_size, void* d_ws, size_t ws_size,
                              hipStream_t stream) {
    const float* x      = (const float*)d_in[0];
    const int*   ei     = (const int*)d_in[1];
    const float* pseudo = (const float*)d_in[2];
    const float* weight = (const float*)d_in[3];
    const float* bias   = (const float*)d_in[4];
    float* out = (float*)d_out;

    // workspace layout (bytes)
    char* ws = (char*)d_ws;
    int* cnt       = (int*)(ws + 0);                 // N ints
    int* fill_pos  = (int*)(ws + 80000);             // N ints
    int* row_start = (int*)(ws + 160000);            // N+1 ints
    int* col_sorted   = (int*)(ws + 240128);         // E ints
    int* kpack_sorted = (int*)(ws + 2240128);        // E ints
    float4* basis_sorted = (float4*)(ws + 4240128);  // E float4 -> ends 12240128
    ushort* wb = (ushort*)(ws + 12240128);           // 26*2*4*64*16B = 212992
    ushort* zb = (ushort*)(ws + 12453120);           // 20000*1664*2 = 66.56 MB
    // total ws needed: ~79.0 MB

    hipMemsetAsync(ws, 0, 160000, stream);           // cnt + fill_pos

    int eb = (N_EDGES + 255) / 256;
    k_hist<<<eb, 256, 0, stream>>>(ei, cnt);
    k_scan<<<1, 1024, 0, stream>>>(cnt, row_start);
    k_fill<<<eb, 256, 0, stream>>>(ei, pseudo, row_start, fill_pos,
                                   col_sorted, kpack_sorted, basis_sorted);
    k_prep<<<(NK * 2 * 4 * 64 + 255) / 256, 256, 0, stream>>>(weight, wb);
    k_z<<<N_NODES / 16, 256, 0, stream>>>(x, wb, zb);
    k_out<<<(N_NODES + 3) / 4, 256, 0, stream>>>(zb, bias, row_start,
                                                 col_sorted, kpack_sorted,
                                                 basis_sorted, out);
}

// Round 5
// 218.278 us; speedup vs baseline: 1.7532x; 1.0894x over previous
//
#include <hip/hip_runtime.h>
#include <hip/hip_bf16.h>
#include <cstdint>

// Problem constants (match reference)
constexpr int N_NODES = 20000;
constexpr int N_EDGES = 500000;
constexpr int IN_F    = 64;
constexpr int OUT_F   = 64;
constexpr int KS      = 5;
constexpr int K_MATS  = 25;    // spline kernel matrices
constexpr int NK      = 26;    // + root weight
constexpr int ZSTRIDE = NK * OUT_F;  // 1664

typedef __attribute__((ext_vector_type(8))) short short8;
typedef __attribute__((ext_vector_type(4))) float f32x4;

__device__ __forceinline__ ushort f2bf(float f) {   // RNE float->bf16 bits
    union { float f; uint32_t u; } c; c.f = f;
    uint32_t u = c.u + 0x7FFFu + ((c.u >> 16) & 1u);
    return (ushort)(u >> 16);
}
__device__ __forceinline__ float bf2f(ushort s) {
    union { uint32_t u; float f; } c; c.u = ((uint32_t)s) << 16;
    return c.f;
}

// ---------------- CSR build ----------------

__global__ void k_hist(const int* __restrict__ ei, int* __restrict__ cnt) {
    int e = blockIdx.x * blockDim.x + threadIdx.x;
    if (e < N_EDGES) atomicAdd(&cnt[ei[e]], 1);
}

__global__ __launch_bounds__(1024) void k_scan(const int* __restrict__ cnt,
                                               int* __restrict__ row_start) {
    __shared__ int sums[1024];
    const int T = 1024;
    int tid = threadIdx.x;
    const int per = (N_NODES + T - 1) / T;   // 20
    int base = tid * per;
    int s = 0;
    for (int j = 0; j < per; ++j) {
        int idx = base + j;
        if (idx < N_NODES) s += cnt[idx];
    }
    sums[tid] = s;
    __syncthreads();
    for (int off = 1; off < T; off <<= 1) {
        int v = (tid >= off) ? sums[tid - off] : 0;
        __syncthreads();
        sums[tid] += v;
        __syncthreads();
    }
    int run = (tid == 0) ? 0 : sums[tid - 1];
    for (int j = 0; j < per; ++j) {
        int idx = base + j;
        if (idx < N_NODES) { row_start[idx] = run; run += cnt[idx]; }
    }
    if (tid == T - 1) row_start[N_NODES] = run;
}

// Per-edge spline basis; records: int2{col,kpack} + float4 basis (2 scattered lines/edge)
__global__ void k_fill(const int* __restrict__ ei, const float* __restrict__ pseudo,
                       const int* __restrict__ row_start, int* __restrict__ fill_pos,
                       int2* __restrict__ colkp, float4* __restrict__ basis_sorted) {
    int e = blockIdx.x * blockDim.x + threadIdx.x;
    if (e >= N_EDGES) return;
    int row = ei[e];
    int col = ei[N_EDGES + e];
    float u0 = pseudo[2 * e]     * (float)(KS - 1);
    float u1 = pseudo[2 * e + 1] * (float)(KS - 1);
    int i0 = min(max((int)floorf(u0), 0), KS - 2);
    int i1 = min(max((int)floorf(u1), 0), KS - 2);
    float f0 = u0 - (float)i0;
    float f1 = u1 - (float)i1;
    float b00 = (1.f - f0) * (1.f - f1);
    float b10 = f0 * (1.f - f1);
    float b01 = (1.f - f0) * f1;
    float b11 = f0 * f1;
    int k00 = i0 * KS + i1;
    int k10 = (i0 + 1) * KS + i1;
    int k01 = i0 * KS + (i1 + 1);
    int k11 = (i0 + 1) * KS + (i1 + 1);
    int pos = row_start[row] + atomicAdd(&fill_pos[row], 1);
    colkp[pos] = make_int2(col, k00 | (k10 << 8) | (k01 << 16) | (k11 << 24));
    basis_sorted[pos] = make_float4(b00, b10, b01, b11);
}

// ---------------- W repack into MFMA B-fragment order (bf16) ----------------
__global__ void k_prep(const float* __restrict__ w, ushort* __restrict__ wb) {
    int t = blockIdx.x * blockDim.x + threadIdx.x;   // one 16B slot
    if (t >= NK * 2 * 4 * 64) return;
    int lane = t & 63;
    int nf   = (t >> 6) & 3;
    int ks   = (t >> 8) & 1;
    int k    = t >> 9;
    int kk0  = ks * 32 + (lane >> 4) * 8;
    int col  = nf * 16 + (lane & 15);
    ushort v[8];
#pragma unroll
    for (int j = 0; j < 8; ++j)
        v[j] = f2bf(w[(k * 64 + kk0 + j) * 64 + col]);
    uint4 p;
    p.x = (uint32_t)v[0] | ((uint32_t)v[1] << 16);
    p.y = (uint32_t)v[2] | ((uint32_t)v[3] << 16);
    p.z = (uint32_t)v[4] | ((uint32_t)v[5] << 16);
    p.w = (uint32_t)v[6] | ((uint32_t)v[7] << 16);
    ((uint4*)wb)[t] = p;
}

// ---------------- Z = x @ W[k] for all 26 k, via MFMA ----------------
__global__ __launch_bounds__(256) void k_z(const float* __restrict__ x,
                                           const ushort* __restrict__ wb,
                                           ushort* __restrict__ z) {
    int lane = threadIdx.x & 63;
    int wave = threadIdx.x >> 6;
    int node0 = blockIdx.x * 16;
    int r  = lane & 15;
    int kg = lane >> 4;

    short8 a[2];
#pragma unroll
    for (int ks = 0; ks < 2; ++ks) {
        const float4* xp = (const float4*)(x + (node0 + r) * IN_F + ks * 32 + kg * 8);
        float4 x0 = xp[0];
        float4 x1 = xp[1];
        short8 af;
        af[0] = (short)f2bf(x0.x); af[1] = (short)f2bf(x0.y);
        af[2] = (short)f2bf(x0.z); af[3] = (short)f2bf(x0.w);
        af[4] = (short)f2bf(x1.x); af[5] = (short)f2bf(x1.y);
        af[6] = (short)f2bf(x1.z); af[7] = (short)f2bf(x1.w);
        a[ks] = af;
    }

    for (int k = wave; k < NK; k += 4) {
        f32x4 acc[4];
#pragma unroll
        for (int nf = 0; nf < 4; ++nf) acc[nf] = (f32x4){0.f, 0.f, 0.f, 0.f};

#pragma unroll
        for (int ks = 0; ks < 2; ++ks) {
#pragma unroll
            for (int nf = 0; nf < 4; ++nf) {
                union { uint4 u; short8 s; } b;
                b.u = *(const uint4*)(wb + ((((size_t)k * 2 + ks) * 4 + nf) * 64 + lane) * 8);
                acc[nf] = __builtin_amdgcn_mfma_f32_16x16x32_bf16(a[ks], b.s, acc[nf], 0, 0, 0);
            }
        }
        int rowbase = (lane >> 4) * 4;
#pragma unroll
        for (int nf = 0; nf < 4; ++nf) {
#pragma unroll
            for (int rg = 0; rg < 4; ++rg) {
                int row = rowbase + rg;
                z[(size_t)(node0 + row) * ZSTRIDE + k * 64 + nf * 16 + (lane & 15)] =
                    f2bf(acc[nf][rg]);
            }
        }
    }
}

// ---------------- Per-node gather-aggregate + epilogue ----------------
// One wave per node, acc in registers (lane = out channel). Edge loop
// unrolled x4: 8 record loads + 16 Z-gathers in flight per iteration.
__global__ __launch_bounds__(256) void k_out(const ushort* __restrict__ z,
        const float* __restrict__ bias, const int* __restrict__ row_start,
        const int2* __restrict__ colkp, const float4* __restrict__ basis4,
        float* __restrict__ out) {
    int lane = threadIdx.x & 63;
    int n = blockIdx.x * 4 + (threadIdx.x >> 6);
    if (n >= N_NODES) return;
    int e0 = row_start[n], e1 = row_start[n + 1];
    float acc0 = 0.f, acc1 = 0.f;
    int e = e0;
    for (; e + 4 <= e1; e += 4) {
        int2   ck0 = colkp[e],     ck1 = colkp[e + 1];
        int2   ck2 = colkp[e + 2], ck3 = colkp[e + 3];
        float4 b0 = basis4[e],     b1 = basis4[e + 1];
        float4 b2 = basis4[e + 2], b3 = basis4[e + 3];
        const ushort* z0 = z + (size_t)ck0.x * ZSTRIDE;
        const ushort* z1 = z + (size_t)ck1.x * ZSTRIDE;
        const ushort* z2 = z + (size_t)ck2.x * ZSTRIDE;
        const ushort* z3 = z + (size_t)ck3.x * ZSTRIDE;
        float v00 = bf2f(z0[((ck0.y      ) & 255) * 64 + lane]);
        float v01 = bf2f(z0[((ck0.y >> 8 ) & 255) * 64 + lane]);
        float v02 = bf2f(z0[((ck0.y >> 16) & 255) * 64 + lane]);
        float v03 = bf2f(z0[((ck0.y >> 24) & 255) * 64 + lane]);
        float v10 = bf2f(z1[((ck1.y      ) & 255) * 64 + lane]);
        float v11 = bf2f(z1[((ck1.y >> 8 ) & 255) * 64 + lane]);
        float v12 = bf2f(z1[((ck1.y >> 16) & 255) * 64 + lane]);
        float v13 = bf2f(z1[((ck1.y >> 24) & 255) * 64 + lane]);
        float v20 = bf2f(z2[((ck2.y      ) & 255) * 64 + lane]);
        float v21 = bf2f(z2[((ck2.y >> 8 ) & 255) * 64 + lane]);
        float v22 = bf2f(z2[((ck2.y >> 16) & 255) * 64 + lane]);
        float v23 = bf2f(z2[((ck2.y >> 24) & 255) * 64 + lane]);
        float v30 = bf2f(z3[((ck3.y      ) & 255) * 64 + lane]);
        float v31 = bf2f(z3[((ck3.y >> 8 ) & 255) * 64 + lane]);
        float v32 = bf2f(z3[((ck3.y >> 16) & 255) * 64 + lane]);
        float v33 = bf2f(z3[((ck3.y >> 24) & 255) * 64 + lane]);
        acc0 += b0.x * v00 + b0.y * v01 + b0.z * v02 + b0.w * v03;
        acc1 += b1.x * v10 + b1.y * v11 + b1.z * v12 + b1.w * v13;
        acc0 += b2.x * v20 + b2.y * v21 + b2.z * v22 + b2.w * v23;
        acc1 += b3.x * v30 + b3.y * v31 + b3.z * v32 + b3.w * v33;
    }
    for (; e < e1; ++e) {
        int2   ck = colkp[e];
        float4 b  = basis4[e];
        const ushort* zb = z + (size_t)ck.x * ZSTRIDE;
        float v0 = bf2f(zb[((ck.y      ) & 255) * 64 + lane]);
        float v1 = bf2f(zb[((ck.y >> 8 ) & 255) * 64 + lane]);
        float v2 = bf2f(zb[((ck.y >> 16) & 255) * 64 + lane]);
        float v3 = bf2f(zb[((ck.y >> 24) & 255) * 64 + lane]);
        acc0 += b.x * v0 + b.y * v1 + b.z * v2 + b.w * v3;
    }
    int deg = e1 - e0;
    float root = bf2f(z[(size_t)n * ZSTRIDE + K_MATS * 64 + lane]);
    out[n * OUT_F + lane] = (acc0 + acc1) / (float)max(deg, 1) + root + bias[lane];
}

// ---------------- launch ----------------

extern "C" void kernel_launch(void* const* d_in, const int* in_sizes, int n_in,
                              void* d_out, int out_size, void* d_ws, size_t ws_size,
                              hipStream_t stream) {
    const float* x      = (const float*)d_in[0];
    const int*   ei     = (const int*)d_in[1];
    const float* pseudo = (const float*)d_in[2];
    const float* weight = (const float*)d_in[3];
    const float* bias   = (const float*)d_in[4];
    float* out = (float*)d_out;

    // workspace layout (bytes) — identical footprint to R4 (proven to fit)
    char* ws = (char*)d_ws;
    int* cnt       = (int*)(ws + 0);                 // N ints
    int* fill_pos  = (int*)(ws + 80000);             // N ints
    int* row_start = (int*)(ws + 160000);            // N+1 ints
    int2* colkp    = (int2*)(ws + 240128);           // E int2 (8B) -> ends 4240128
    float4* basis_sorted = (float4*)(ws + 4240128);  // E float4   -> ends 12240128
    ushort* wb = (ushort*)(ws + 12240128);           // 26*2*4*64*16B = 212992
    ushort* zb = (ushort*)(ws + 12453120);           // 20000*1664*2 = 66.56 MB

    hipMemsetAsync(ws, 0, 160000, stream);           // cnt + fill_pos

    int eb = (N_EDGES + 255) / 256;
    k_hist<<<eb, 256, 0, stream>>>(ei, cnt);
    k_scan<<<1, 1024, 0, stream>>>(cnt, row_start);
    k_fill<<<eb, 256, 0, stream>>>(ei, pseudo, row_start, fill_pos,
                                   colkp, basis_sorted);
    k_prep<<<(NK * 2 * 4 * 64 + 255) / 256, 256, 0, stream>>>(weight, wb);
    k_z<<<N_NODES / 16, 256, 0, stream>>>(x, wb, zb);
    k_out<<<(N_NODES + 3) / 4, 256, 0, stream>>>(zb, bias, row_start,
                                                 colkp, basis_sorted, out);
}

// Round 6
// 209.701 us; speedup vs baseline: 1.8249x; 1.0409x over previous
//
#include <hip/hip_runtime.h>
#include <hip/hip_bf16.h>
#include <cstdint>

// Problem constants (match reference)
constexpr int N_NODES = 20000;
constexpr int N_EDGES = 500000;
constexpr int IN_F    = 64;
constexpr int OUT_F   = 64;
constexpr int KS      = 5;
constexpr int K_MATS  = 25;    // spline kernel matrices
constexpr int NK      = 26;    // + root weight
// Z layout: [node/16][k][node%16][64ch] bf16 -> 2048 B per (tile,k) region
constexpr int ZTILE_USH = 1024;          // ushorts per (tile,k)

typedef __attribute__((ext_vector_type(8))) short short8;
typedef __attribute__((ext_vector_type(4))) float f32x4;

__device__ __forceinline__ ushort f2bf(float f) {   // RNE float->bf16 bits
    union { float f; uint32_t u; } c; c.f = f;
    uint32_t u = c.u + 0x7FFFu + ((c.u >> 16) & 1u);
    return (ushort)(u >> 16);
}
__device__ __forceinline__ float bf2f(uint32_t s) { // low 16 bits = bf16
    union { uint32_t u; float f; } c; c.u = (s & 0xFFFFu) << 16;
    return c.f;
}

// ---------------- fused W-repack + degree histogram (independent leaves) ----
// blocks [0,208): repack weight into MFMA B-frag order (bf16)
// blocks [208, 208+1954): histogram of edge targets
constexpr int PREP_BLOCKS = (NK * 2 * 4 * 64) / 256;       // 208
constexpr int HIST_BLOCKS = (N_EDGES + 255) / 256;         // 1954

__global__ void k_ph(const float* __restrict__ w, ushort* __restrict__ wb,
                     const int* __restrict__ ei, int* __restrict__ cnt) {
    int b = blockIdx.x;
    if (b < PREP_BLOCKS) {
        int t = b * 256 + threadIdx.x;   // one 16B B-frag slot
        int lane = t & 63;
        int nf   = (t >> 6) & 3;
        int ks   = (t >> 8) & 1;
        int k    = t >> 9;
        int kk0  = ks * 32 + (lane >> 4) * 8;
        int col  = nf * 16 + (lane & 15);
        ushort v[8];
#pragma unroll
        for (int j = 0; j < 8; ++j)
            v[j] = f2bf(w[(k * 64 + kk0 + j) * 64 + col]);
        uint4 p;
        p.x = (uint32_t)v[0] | ((uint32_t)v[1] << 16);
        p.y = (uint32_t)v[2] | ((uint32_t)v[3] << 16);
        p.z = (uint32_t)v[4] | ((uint32_t)v[5] << 16);
        p.w = (uint32_t)v[6] | ((uint32_t)v[7] << 16);
        ((uint4*)wb)[t] = p;
    } else {
        int e = (b - PREP_BLOCKS) * 256 + threadIdx.x;
        if (e < N_EDGES) atomicAdd(&cnt[ei[e]], 1);
    }
}

// ---------------- exclusive scan (single block) ----------------
__global__ __launch_bounds__(1024) void k_scan(const int* __restrict__ cnt,
                                               int* __restrict__ row_start) {
    __shared__ int sums[1024];
    const int T = 1024;
    int tid = threadIdx.x;
    const int per = (N_NODES + T - 1) / T;   // 20
    int base = tid * per;
    int s = 0;
    for (int j = 0; j < per; ++j) {
        int idx = base + j;
        if (idx < N_NODES) s += cnt[idx];
    }
    sums[tid] = s;
    __syncthreads();
    for (int off = 1; off < T; off <<= 1) {
        int v = (tid >= off) ? sums[tid - off] : 0;
        __syncthreads();
        sums[tid] += v;
        __syncthreads();
    }
    int run = (tid == 0) ? 0 : sums[tid - 1];
    for (int j = 0; j < per; ++j) {
        int idx = base + j;
        if (idx < N_NODES) { row_start[idx] = run; run += cnt[idx]; }
    }
    if (tid == T - 1) row_start[N_NODES] = run;
}

// ---------------- per-edge basis -> 16-B sorted record ----------------
// rec = {col, kpack, bf16x2(b00,b10), bf16x2(b01,b11)} : ONE dwordx4 scatter
__global__ void k_fill(const int* __restrict__ ei, const float* __restrict__ pseudo,
                       const int* __restrict__ row_start, int* __restrict__ fill_pos,
                       uint4* __restrict__ rec) {
    int e = blockIdx.x * blockDim.x + threadIdx.x;
    if (e >= N_EDGES) return;
    int row = ei[e];
    int col = ei[N_EDGES + e];
    float u0 = pseudo[2 * e]     * (float)(KS - 1);
    float u1 = pseudo[2 * e + 1] * (float)(KS - 1);
    int i0 = min(max((int)floorf(u0), 0), KS - 2);
    int i1 = min(max((int)floorf(u1), 0), KS - 2);
    float f0 = u0 - (float)i0;
    float f1 = u1 - (float)i1;
    float b00 = (1.f - f0) * (1.f - f1);
    float b10 = f0 * (1.f - f1);
    float b01 = (1.f - f0) * f1;
    float b11 = f0 * f1;
    int k00 = i0 * KS + i1;
    int k10 = (i0 + 1) * KS + i1;
    int k01 = k00 + 1;
    int k11 = k10 + 1;
    int pos = row_start[row] + atomicAdd(&fill_pos[row], 1);
    uint4 r;
    r.x = (uint32_t)col;
    r.y = (uint32_t)(k00 | (k10 << 8) | (k01 << 16) | (k11 << 24));
    r.z = (uint32_t)f2bf(b00) | ((uint32_t)f2bf(b10) << 16);
    r.w = (uint32_t)f2bf(b01) | ((uint32_t)f2bf(b11) << 16);
    rec[pos] = r;
}

// ---------------- Z = x @ W[k] for all 26 k, via MFMA ----------------
// Tiled Z layout; per-wave LDS bounce -> fully coalesced 2-KB tile stores.
__global__ __launch_bounds__(256) void k_z(const float* __restrict__ x,
                                           const ushort* __restrict__ wb,
                                           ushort* __restrict__ z) {
    __shared__ float lds[4][16][66];   // per-wave bounce, stride 66 -> 2-way banks (free)
    int lane = threadIdx.x & 63;
    int wave = threadIdx.x >> 6;
    int tile = blockIdx.x;
    int node0 = tile * 16;
    int r  = lane & 15;
    int kg = lane >> 4;

    short8 a[2];
#pragma unroll
    for (int ks = 0; ks < 2; ++ks) {
        const float4* xp = (const float4*)(x + (node0 + r) * IN_F + ks * 32 + kg * 8);
        float4 x0 = xp[0];
        float4 x1 = xp[1];
        short8 af;
        af[0] = (short)f2bf(x0.x); af[1] = (short)f2bf(x0.y);
        af[2] = (short)f2bf(x0.z); af[3] = (short)f2bf(x0.w);
        af[4] = (short)f2bf(x1.x); af[5] = (short)f2bf(x1.y);
        af[6] = (short)f2bf(x1.z); af[7] = (short)f2bf(x1.w);
        a[ks] = af;
    }

    for (int k = wave; k < NK; k += 4) {
        f32x4 acc[4];
#pragma unroll
        for (int nf = 0; nf < 4; ++nf) acc[nf] = (f32x4){0.f, 0.f, 0.f, 0.f};

#pragma unroll
        for (int ks = 0; ks < 2; ++ks) {
#pragma unroll
            for (int nf = 0; nf < 4; ++nf) {
                union { uint4 u; short8 s; } b;
                b.u = *(const uint4*)(wb + ((((size_t)k * 2 + ks) * 4 + nf) * 64 + lane) * 8);
                acc[nf] = __builtin_amdgcn_mfma_f32_16x16x32_bf16(a[ks], b.s, acc[nf], 0, 0, 0);
            }
        }
        // D-frag (row = 4*kg + rg, col = nf*16 + r) -> per-wave LDS tile (f32)
#pragma unroll
        for (int nf = 0; nf < 4; ++nf)
#pragma unroll
            for (int rg = 0; rg < 4; ++rg)
                lds[wave][kg * 4 + rg][nf * 16 + r] = acc[nf][rg];
        // order LDS writes before cross-lane reads (wave-private region; DS in-order)
        asm volatile("s_waitcnt lgkmcnt(0)" ::: "memory");
        __builtin_amdgcn_sched_barrier(0);
        // lane l -> node i=l>>2, ch block (l&3)*16 : 16 f32 contiguous
        const float* lrow = &lds[wave][lane >> 2][(lane & 3) * 16];
        float v[16];
#pragma unroll
        for (int j = 0; j < 16; ++j) v[j] = lrow[j];
        uint32_t pk[8];
#pragma unroll
        for (int j = 0; j < 8; ++j)
            pk[j] = (uint32_t)f2bf(v[2 * j]) | ((uint32_t)f2bf(v[2 * j + 1]) << 16);
        uint4* dst = (uint4*)(z + (size_t)(tile * NK + k) * ZTILE_USH + lane * 16);
        dst[0] = make_uint4(pk[0], pk[1], pk[2], pk[3]);
        dst[1] = make_uint4(pk[4], pk[5], pk[6], pk[7]);
        // keep next iter's LDS writes ordered after this iter's reads
        asm volatile("" ::: "memory");
    }
}

// ---------------- Per-node gather-aggregate + epilogue ----------------
// One wave per node; unroll 8 -> 32 outstanding Z-gathers + 8 record loads.
__global__ __launch_bounds__(256) void k_out(const ushort* __restrict__ z,
        const float* __restrict__ bias, const int* __restrict__ row_start,
        const uint4* __restrict__ rec, float* __restrict__ out) {
    int lane = threadIdx.x & 63;
    int n = blockIdx.x * 4 + (threadIdx.x >> 6);
    if (n >= N_NODES) return;
    int e0 = row_start[n], e1 = row_start[n + 1];
    float acc0 = 0.f, acc1 = 0.f;
    int e = e0;
    for (; e + 8 <= e1; e += 8) {
        uint4 rr[8];
#pragma unroll
        for (int t = 0; t < 8; ++t) rr[t] = rec[e + t];
        float vv[8][4];
#pragma unroll
        for (int t = 0; t < 8; ++t) {
            uint32_t kp = rr[t].y;
            const ushort* zb = z + (size_t)(rr[t].x >> 4) * (NK * ZTILE_USH)
                                 + (rr[t].x & 15) * 64 + lane;
            vv[t][0] = bf2f((uint32_t)zb[((kp      ) & 255) * ZTILE_USH]);
            vv[t][1] = bf2f((uint32_t)zb[((kp >> 8 ) & 255) * ZTILE_USH]);
            vv[t][2] = bf2f((uint32_t)zb[((kp >> 16) & 255) * ZTILE_USH]);
            vv[t][3] = bf2f((uint32_t)zb[((kp >> 24)      ) * ZTILE_USH]);
        }
#pragma unroll
        for (int t = 0; t < 8; ++t) {
            float b0 = bf2f(rr[t].z), b1 = bf2f(rr[t].z >> 16);
            float b2 = bf2f(rr[t].w), b3 = bf2f(rr[t].w >> 16);
            float s = b0 * vv[t][0] + b1 * vv[t][1] + b2 * vv[t][2] + b3 * vv[t][3];
            if (t & 1) acc1 += s; else acc0 += s;
        }
    }
    for (; e + 4 <= e1; e += 4) {
        uint4 rr[4];
#pragma unroll
        for (int t = 0; t < 4; ++t) rr[t] = rec[e + t];
        float vv[4][4];
#pragma unroll
        for (int t = 0; t < 4; ++t) {
            uint32_t kp = rr[t].y;
            const ushort* zb = z + (size_t)(rr[t].x >> 4) * (NK * ZTILE_USH)
                                 + (rr[t].x & 15) * 64 + lane;
            vv[t][0] = bf2f((uint32_t)zb[((kp      ) & 255) * ZTILE_USH]);
            vv[t][1] = bf2f((uint32_t)zb[((kp >> 8 ) & 255) * ZTILE_USH]);
            vv[t][2] = bf2f((uint32_t)zb[((kp >> 16) & 255) * ZTILE_USH]);
            vv[t][3] = bf2f((uint32_t)zb[((kp >> 24)      ) * ZTILE_USH]);
        }
#pragma unroll
        for (int t = 0; t < 4; ++t) {
            float b0 = bf2f(rr[t].z), b1 = bf2f(rr[t].z >> 16);
            float b2 = bf2f(rr[t].w), b3 = bf2f(rr[t].w >> 16);
            float s = b0 * vv[t][0] + b1 * vv[t][1] + b2 * vv[t][2] + b3 * vv[t][3];
            if (t & 1) acc1 += s; else acc0 += s;
        }
    }
    for (; e < e1; ++e) {
        uint4 r = rec[e];
        uint32_t kp = r.y;
        const ushort* zb = z + (size_t)(r.x >> 4) * (NK * ZTILE_USH)
                             + (r.x & 15) * 64 + lane;
        float v0 = bf2f((uint32_t)zb[((kp      ) & 255) * ZTILE_USH]);
        float v1 = bf2f((uint32_t)zb[((kp >> 8 ) & 255) * ZTILE_USH]);
        float v2 = bf2f((uint32_t)zb[((kp >> 16) & 255) * ZTILE_USH]);
        float v3 = bf2f((uint32_t)zb[((kp >> 24)      ) * ZTILE_USH]);
        acc0 += bf2f(r.z) * v0 + bf2f(r.z >> 16) * v1
              + bf2f(r.w) * v2 + bf2f(r.w >> 16) * v3;
    }
    int deg = e1 - e0;
    float root = bf2f((uint32_t)z[(size_t)((n >> 4) * NK + K_MATS) * ZTILE_USH
                                  + (n & 15) * 64 + lane]);
    out[n * OUT_F + lane] = (acc0 + acc1) / (float)max(deg, 1) + root + bias[lane];
}

// ---------------- launch ----------------

extern "C" void kernel_launch(void* const* d_in, const int* in_sizes, int n_in,
                              void* d_out, int out_size, void* d_ws, size_t ws_size,
                              hipStream_t stream) {
    const float* x      = (const float*)d_in[0];
    const int*   ei     = (const int*)d_in[1];
    const float* pseudo = (const float*)d_in[2];
    const float* weight = (const float*)d_in[3];
    const float* bias   = (const float*)d_in[4];
    float* out = (float*)d_out;

    // workspace layout (bytes); total ~75 MB (79 MB proven to fit in R4/R5)
    char* ws = (char*)d_ws;
    int* cnt       = (int*)(ws + 0);            // N ints
    int* fill_pos  = (int*)(ws + 80000);        // N ints
    int* row_start = (int*)(ws + 160000);       // N+1 ints
    uint4* rec     = (uint4*)(ws + 240128);     // E * 16 B          -> ends 8240128
    ushort* wb     = (ushort*)(ws + 8240128);   // 26*2*4*64*16 B    -> ends 8453120
    ushort* zb     = (ushort*)(ws + 8453120);   // 1250*26*2048 B    -> ends ~75 MB

    hipMemsetAsync(ws, 0, 160000, stream);      // cnt + fill_pos

    k_ph<<<PREP_BLOCKS + HIST_BLOCKS, 256, 0, stream>>>(weight, wb, ei, cnt);
    k_scan<<<1, 1024, 0, stream>>>(cnt, row_start);
    k_fill<<<HIST_BLOCKS, 256, 0, stream>>>(ei, pseudo, row_start, fill_pos, rec);
    k_z<<<N_NODES / 16, 256, 0, stream>>>(x, wb, zb);
    k_out<<<(N_NODES + 3) / 4, 256, 0, stream>>>(zb, bias, row_start, rec, out);
}

// Round 12
// 209.049 us; speedup vs baseline: 1.8306x; 1.0031x over previous
//
#include <hip/hip_runtime.h>
#include <hip/hip_bf16.h>
#include <cstdint>

// Problem constants (match reference)
constexpr int N_NODES = 20000;
constexpr int N_EDGES = 500000;
constexpr int IN_F    = 64;
constexpr int OUT_F   = 64;
constexpr int KS      = 5;
constexpr int K_MATS  = 25;    // spline kernel matrices
constexpr int NK      = 26;    // + root weight
// Z layout: [node/16][k][node%16][64ch] bf16 -> 2048 B per (tile,k) region
constexpr int ZTILE_USH = 1024;          // ushorts per (tile,k)

typedef __attribute__((ext_vector_type(8))) short short8;
typedef __attribute__((ext_vector_type(4))) float f32x4;

__device__ __forceinline__ ushort f2bf(float f) {   // RNE float->bf16 bits
    union { float f; uint32_t u; } c; c.f = f;
    uint32_t u = c.u + 0x7FFFu + ((c.u >> 16) & 1u);
    return (ushort)(u >> 16);
}
__device__ __forceinline__ float bf2f(uint32_t s) { // low 16 bits = bf16
    union { uint32_t u; float f; } c; c.u = (s & 0xFFFFu) << 16;
    return c.f;
}

// NOTE (R11 post-mortem): the {k_z+k_fill fusion, rank-based fill} bundle
// failed validation (absmax 0.057 vs R6's 0.0117) with a verbatim R6 k_out —
// both deltas reverted. This file is the R6-passing structure exactly, with
// ONE change: k_out uses uniform-base + u32-index gather addressing.

// ---------------- fused W-repack + degree histogram (R6-proven) ------------
constexpr int PREP_BLOCKS = (NK * 2 * 4 * 64) / 256;       // 208
constexpr int HIST_BLOCKS = (N_EDGES + 255) / 256;         // 1954

__global__ void k_ph(const float* __restrict__ w, ushort* __restrict__ wb,
                     const int* __restrict__ ei, int* __restrict__ cnt) {
    int b = blockIdx.x;
    if (b < PREP_BLOCKS) {
        int t = b * 256 + threadIdx.x;   // one 16B B-frag slot
        int lane = t & 63;
        int nf   = (t >> 6) & 3;
        int ks   = (t >> 8) & 1;
        int k    = t >> 9;
        int kk0  = ks * 32 + (lane >> 4) * 8;
        int col  = nf * 16 + (lane & 15);
        ushort v[8];
#pragma unroll
        for (int j = 0; j < 8; ++j)
            v[j] = f2bf(w[(k * 64 + kk0 + j) * 64 + col]);
        uint4 p;
        p.x = (uint32_t)v[0] | ((uint32_t)v[1] << 16);
        p.y = (uint32_t)v[2] | ((uint32_t)v[3] << 16);
        p.z = (uint32_t)v[4] | ((uint32_t)v[5] << 16);
        p.w = (uint32_t)v[6] | ((uint32_t)v[7] << 16);
        ((uint4*)wb)[t] = p;
    } else {
        int e = (b - PREP_BLOCKS) * 256 + threadIdx.x;
        if (e < N_EDGES) atomicAdd(&cnt[ei[e]], 1);
    }
}

// ---------------- exclusive scan (single block, R6-proven) ----------------
__global__ __launch_bounds__(1024) void k_scan(const int* __restrict__ cnt,
                                               int* __restrict__ row_start) {
    __shared__ int sums[1024];
    const int T = 1024;
    int tid = threadIdx.x;
    const int per = (N_NODES + T - 1) / T;   // 20
    int base = tid * per;
    int s = 0;
    for (int j = 0; j < per; ++j) {
        int idx = base + j;
        if (idx < N_NODES) s += cnt[idx];
    }
    sums[tid] = s;
    __syncthreads();
    for (int off = 1; off < T; off <<= 1) {
        int v = (tid >= off) ? sums[tid - off] : 0;
        __syncthreads();
        sums[tid] += v;
        __syncthreads();
    }
    int run = (tid == 0) ? 0 : sums[tid - 1];
    for (int j = 0; j < per; ++j) {
        int idx = base + j;
        if (idx < N_NODES) { row_start[idx] = run; run += cnt[idx]; }
    }
    if (tid == T - 1) row_start[N_NODES] = run;
}

// ---------------- per-edge basis -> 16-B sorted record (R6-proven) ---------
__global__ void k_fill(const int* __restrict__ ei, const float* __restrict__ pseudo,
                       const int* __restrict__ row_start, int* __restrict__ fill_pos,
                       uint4* __restrict__ rec) {
    int e = blockIdx.x * blockDim.x + threadIdx.x;
    if (e >= N_EDGES) return;
    int row = ei[e];
    int col = ei[N_EDGES + e];
    float u0 = pseudo[2 * e]     * (float)(KS - 1);
    float u1 = pseudo[2 * e + 1] * (float)(KS - 1);
    int i0 = min(max((int)floorf(u0), 0), KS - 2);
    int i1 = min(max((int)floorf(u1), 0), KS - 2);
    float f0 = u0 - (float)i0;
    float f1 = u1 - (float)i1;
    float b00 = (1.f - f0) * (1.f - f1);
    float b10 = f0 * (1.f - f1);
    float b01 = (1.f - f0) * f1;
    float b11 = f0 * f1;
    int k00 = i0 * KS + i1;
    int k10 = (i0 + 1) * KS + i1;
    int pos = row_start[row] + atomicAdd(&fill_pos[row], 1);
    uint4 r;
    r.x = (uint32_t)col;
    r.y = (uint32_t)(k00 | (k10 << 8) | ((k00 + 1) << 16) | ((k10 + 1) << 24));
    r.z = (uint32_t)f2bf(b00) | ((uint32_t)f2bf(b10) << 16);
    r.w = (uint32_t)f2bf(b01) | ((uint32_t)f2bf(b11) << 16);
    rec[pos] = r;
}

// ---------------- Z = x @ W[k] via MFMA (R6-proven) ----------------
constexpr int ZBLKS = N_NODES / 16;     // 1250

__global__ __launch_bounds__(256) void k_z(const float* __restrict__ x,
                                           const ushort* __restrict__ wb,
                                           ushort* __restrict__ z) {
    __shared__ float lds[4][16][66];   // per-wave bounce, stride 66
    int lane = threadIdx.x & 63;
    int wave = threadIdx.x >> 6;
    int tile = blockIdx.x;
    int node0 = tile * 16;
    int r  = lane & 15;
    int kg = lane >> 4;

    short8 a[2];
#pragma unroll
    for (int ks = 0; ks < 2; ++ks) {
        const float4* xp = (const float4*)(x + (node0 + r) * IN_F + ks * 32 + kg * 8);
        float4 x0 = xp[0];
        float4 x1 = xp[1];
        short8 af;
        af[0] = (short)f2bf(x0.x); af[1] = (short)f2bf(x0.y);
        af[2] = (short)f2bf(x0.z); af[3] = (short)f2bf(x0.w);
        af[4] = (short)f2bf(x1.x); af[5] = (short)f2bf(x1.y);
        af[6] = (short)f2bf(x1.z); af[7] = (short)f2bf(x1.w);
        a[ks] = af;
    }

    for (int k = wave; k < NK; k += 4) {
        f32x4 acc[4];
#pragma unroll
        for (int nf = 0; nf < 4; ++nf) acc[nf] = (f32x4){0.f, 0.f, 0.f, 0.f};
#pragma unroll
        for (int ks = 0; ks < 2; ++ks) {
#pragma unroll
            for (int nf = 0; nf < 4; ++nf) {
                union { uint4 u; short8 s; } b;
                b.u = *(const uint4*)(wb + ((((size_t)k * 2 + ks) * 4 + nf) * 64 + lane) * 8);
                acc[nf] = __builtin_amdgcn_mfma_f32_16x16x32_bf16(a[ks], b.s, acc[nf], 0, 0, 0);
            }
        }
        // D-frag (row = 4*kg + rg, col = nf*16 + r) -> per-wave LDS tile
#pragma unroll
        for (int nf = 0; nf < 4; ++nf)
#pragma unroll
            for (int rg = 0; rg < 4; ++rg)
                lds[wave][kg * 4 + rg][nf * 16 + r] = acc[nf][rg];
        asm volatile("s_waitcnt lgkmcnt(0)" ::: "memory");
        __builtin_amdgcn_sched_barrier(0);
        const float* lrow = &lds[wave][lane >> 2][(lane & 3) * 16];
        float v[16];
#pragma unroll
        for (int j = 0; j < 16; ++j) v[j] = lrow[j];
        uint32_t pk[8];
#pragma unroll
        for (int j = 0; j < 8; ++j)
            pk[j] = (uint32_t)f2bf(v[2 * j]) | ((uint32_t)f2bf(v[2 * j + 1]) << 16);
        uint4* dst = (uint4*)(z + (size_t)(tile * NK + k) * ZTILE_USH + lane * 16);
        dst[0] = make_uint4(pk[0], pk[1], pk[2], pk[3]);
        dst[1] = make_uint4(pk[4], pk[5], pk[6], pk[7]);
        asm volatile("" ::: "memory");
    }
}

// ---------------- Per-node gather-aggregate + epilogue ----------------
// R6-proven logic; ONLY change: uniform-base + u32-index gather addressing
// (identical indices/values; fewer address VGPRs per in-flight gather).
__global__ __launch_bounds__(256) void k_out(const ushort* __restrict__ z,
        const float* __restrict__ bias, const int* __restrict__ row_start,
        const uint4* __restrict__ rec, float* __restrict__ out) {
    int lane = threadIdx.x & 63;
    int n = blockIdx.x * 4 + (threadIdx.x >> 6);
    if (n >= N_NODES) return;
    int e0 = row_start[n], e1 = row_start[n + 1];
    float acc0 = 0.f, acc1 = 0.f;
    int e = e0;
    for (; e + 8 <= e1; e += 8) {
        uint4 rr[8];
#pragma unroll
        for (int t = 0; t < 8; ++t) rr[t] = rec[e + t];
        float vv[8][4];
#pragma unroll
        for (int t = 0; t < 8; ++t) {
            uint32_t kp = rr[t].y;
            uint32_t base = (rr[t].x >> 4) * (uint32_t)(NK * ZTILE_USH)
                          + (rr[t].x & 15) * 64u + (uint32_t)lane;
            vv[t][0] = bf2f((uint32_t)z[base + ((kp      ) & 255) * 1024u]);
            vv[t][1] = bf2f((uint32_t)z[base + ((kp >> 8 ) & 255) * 1024u]);
            vv[t][2] = bf2f((uint32_t)z[base + ((kp >> 16) & 255) * 1024u]);
            vv[t][3] = bf2f((uint32_t)z[base + ((kp >> 24)      ) * 1024u]);
        }
#pragma unroll
        for (int t = 0; t < 8; ++t) {
            float b0 = bf2f(rr[t].z), b1 = bf2f(rr[t].z >> 16);
            float b2 = bf2f(rr[t].w), b3 = bf2f(rr[t].w >> 16);
            float s = b0 * vv[t][0] + b1 * vv[t][1] + b2 * vv[t][2] + b3 * vv[t][3];
            if (t & 1) acc1 += s; else acc0 += s;
        }
    }
    for (; e + 4 <= e1; e += 4) {
        uint4 rr[4];
#pragma unroll
        for (int t = 0; t < 4; ++t) rr[t] = rec[e + t];
        float vv[4][4];
#pragma unroll
        for (int t = 0; t < 4; ++t) {
            uint32_t kp = rr[t].y;
            uint32_t base = (rr[t].x >> 4) * (uint32_t)(NK * ZTILE_USH)
                          + (rr[t].x & 15) * 64u + (uint32_t)lane;
            vv[t][0] = bf2f((uint32_t)z[base + ((kp      ) & 255) * 1024u]);
            vv[t][1] = bf2f((uint32_t)z[base + ((kp >> 8 ) & 255) * 1024u]);
            vv[t][2] = bf2f((uint32_t)z[base + ((kp >> 16) & 255) * 1024u]);
            vv[t][3] = bf2f((uint32_t)z[base + ((kp >> 24)      ) * 1024u]);
        }
#pragma unroll
        for (int t = 0; t < 4; ++t) {
            float b0 = bf2f(rr[t].z), b1 = bf2f(rr[t].z >> 16);
            float b2 = bf2f(rr[t].w), b3 = bf2f(rr[t].w >> 16);
            float s = b0 * vv[t][0] + b1 * vv[t][1] + b2 * vv[t][2] + b3 * vv[t][3];
            if (t & 1) acc1 += s; else acc0 += s;
        }
    }
    for (; e < e1; ++e) {
        uint4 r = rec[e];
        uint32_t kp = r.y;
        uint32_t base = (r.x >> 4) * (uint32_t)(NK * ZTILE_USH)
                      + (r.x & 15) * 64u + (uint32_t)lane;
        float v0 = bf2f((uint32_t)z[base + ((kp      ) & 255) * 1024u]);
        float v1 = bf2f((uint32_t)z[base + ((kp >> 8 ) & 255) * 1024u]);
        float v2 = bf2f((uint32_t)z[base + ((kp >> 16) & 255) * 1024u]);
        float v3 = bf2f((uint32_t)z[base + ((kp >> 24)      ) * 1024u]);
        acc0 += bf2f(r.z) * v0 + bf2f(r.z >> 16) * v1
              + bf2f(r.w) * v2 + bf2f(r.w >> 16) * v3;
    }
    int deg = e1 - e0;
    uint32_t rbase = ((uint32_t)(n >> 4) * NK + K_MATS) * (uint32_t)ZTILE_USH
                   + (uint32_t)(n & 15) * 64u + (uint32_t)lane;
    float root = bf2f((uint32_t)z[rbase]);
    out[n * OUT_F + lane] = (acc0 + acc1) / (float)max(deg, 1) + root + bias[lane];
}

// ---------------- launch (R6-proven structure) ----------------

extern "C" void kernel_launch(void* const* d_in, const int* in_sizes, int n_in,
                              void* d_out, int out_size, void* d_ws, size_t ws_size,
                              hipStream_t stream) {
    const float* x      = (const float*)d_in[0];
    const int*   ei     = (const int*)d_in[1];
    const float* pseudo = (const float*)d_in[2];
    const float* weight = (const float*)d_in[3];
    const float* bias   = (const float*)d_in[4];
    float* out = (float*)d_out;

    // workspace layout (bytes); ~75 MB total (proven to fit)
    char* ws = (char*)d_ws;
    int* cnt       = (int*)(ws + 0);            // N ints
    int* fill_pos  = (int*)(ws + 80000);        // N ints
    int* row_start = (int*)(ws + 160000);       // N+1 ints
    uint4* rec     = (uint4*)(ws + 240128);     // E * 16 B          -> ends 8240128
    ushort* wb     = (ushort*)(ws + 8240128);   // 26*2*4*64*16 B    -> ends 8453120
    ushort* zb     = (ushort*)(ws + 8453120);   // 1250*26*2048 B    -> ends ~75 MB

    hipMemsetAsync(ws, 0, 160000, stream);      // cnt + fill_pos

    k_ph<<<PREP_BLOCKS + HIST_BLOCKS, 256, 0, stream>>>(weight, wb, ei, cnt);
    k_scan<<<1, 1024, 0, stream>>>(cnt, row_start);
    k_fill<<<HIST_BLOCKS, 256, 0, stream>>>(ei, pseudo, row_start, fill_pos, rec);
    k_z<<<ZBLKS, 256, 0, stream>>>(x, wb, zb);
    k_out<<<(N_NODES + 3) / 4, 256, 0, stream>>>(zb, bias, row_start, rec, out);
}